// Round 3
// baseline (2133.661 us; speedup 1.0000x reference)
//
#include <hip/hip_runtime.h>

// LSTM 2-layer scan: N=1024 independent rows, T=2048 sequential steps.
// Block (256 thr, 4 waves) per batch row; lane quad = 4 gates of one hidden unit.
// R1/R2 lesson: backend targeted max occupancy (VGPR=48) and sank the 52
// loop-invariant weight loads INTO the t-loop (~236 VALU/wave-step vs ~80).
// Fix: amdgpu_waves_per_eu(4,4) raises pressure target to 128 VGPR, plus
// asm pins make the weight loads non-rematerializable.
// h1 double-buffered in LDS; 1 barrier/step. Layer 2 on a rotating wave.

constexpr int H  = 51;
constexpr int TL = 2048;

__device__ __forceinline__ float rcpf(float x) { return __builtin_amdgcn_rcpf(x); }
__device__ __forceinline__ float sigf(float x) { return rcpf(1.0f + __expf(-x)); }
__device__ __forceinline__ float tanhfast(float x) {
    // 1 - 2/(e^{2x}+1); saturates correctly at +-inf
    return 1.0f - 2.0f * rcpf(__expf(x + x) + 1.0f);
}

template <int PAT>
__device__ __forceinline__ float quadb(float v) {
    // DPP quad_perm broadcast of quad-lane k (PAT = k*0x55), pure VALU
    return __int_as_float(__builtin_amdgcn_update_dpp(
        0, __float_as_int(v), PAT, 0xF, 0xF, true));
}

#define PIN4(V) asm volatile("" : "+v"((V).x), "+v"((V).y), "+v"((V).z), "+v"((V).w))

__device__ __forceinline__ void layer2_step(
    const float* __restrict__ hprev, int lane,
    const float4& w2, const float4& wh2, const float4& b2,
    float* __restrict__ c2h2, float* __restrict__ out_ptr)
{
    const float hp = (lane < H) ? hprev[lane] : 0.0f;
    float p0 = w2.x * hp, p1 = w2.y * hp, p2 = w2.z * hp, p3 = w2.w * hp;
    #pragma unroll
    for (int m = 1; m <= 32; m <<= 1) {
        p0 += __shfl_xor(p0, m, 64);
        p1 += __shfl_xor(p1, m, 64);
        p2 += __shfl_xor(p2, m, 64);
        p3 += __shfl_xor(p3, m, 64);
    }
    const float c2 = c2h2[0], h2 = c2h2[1];
    const float a0 = fmaf(wh2.x, h2, p0) + b2.x;
    const float a1 = fmaf(wh2.y, h2, p1) + b2.y;
    const float a2 = fmaf(wh2.z, h2, p2) + b2.z;
    const float a3 = fmaf(wh2.w, h2, p3) + b2.w;
    const float c2n = fmaf(sigf(a1), c2, sigf(a0) * tanhfast(a2));
    const float h2n = sigf(a3) * tanhfast(c2n);
    if (lane == 0) { c2h2[0] = c2n; c2h2[1] = h2n; *out_ptr = h2n; }
}

__global__ void
__attribute__((amdgpu_flat_work_group_size(256, 256)))
__attribute__((amdgpu_waves_per_eu(4, 4)))
lstm2_fused(const float* __restrict__ stim,
            const float* __restrict__ Wih1,
            const float* __restrict__ Whh1,
            const float* __restrict__ bih1,
            const float* __restrict__ bhh1,
            const float* __restrict__ Wih2,
            const float* __restrict__ Whh2,
            const float* __restrict__ bih2,
            const float* __restrict__ bhh2,
            float* __restrict__ out)
{
    const int n    = blockIdx.x;
    const int tid  = threadIdx.x;
    const int wid  = tid >> 6;
    const int lane = tid & 63;
    const int gate = lane & 3;                 // 0=i 1=f 2=g 3=o
    const int unit = wid * 16 + (lane >> 2);   // hidden unit, valid < 51
    const bool uval = (unit < H);

    __shared__ __align__(16) float xrow[TL];
    __shared__ __align__(16) float hbuf[2][56];   // 56: pad so both bufs 16B-aligned
    __shared__ float c2h2[2];

    // ---- stage stimulus row to LDS, coalesced float4 ----
    {
        const float4* s4 = reinterpret_cast<const float4*>(stim + (size_t)n * TL);
        float4* d4 = reinterpret_cast<float4*>(xrow);
        d4[tid]       = s4[tid];
        d4[tid + 256] = s4[tid + 256];
    }

    // ---- layer-1 weights into NAMED float4 registers (one row per thread) ----
    float4 w0, w1, w2_, w3, w4, w5, w6, w7, w8, w9, w10, w11, w12;
    float bsum = 0.0f, wi1 = 0.0f;
    {
        const float4 z = make_float4(0.f, 0.f, 0.f, 0.f);
        w0=z; w1=z; w2_=z; w3=z; w4=z; w5=z; w6=z; w7=z; w8=z; w9=z; w10=z; w11=z; w12=z;
    }
    if (uval) {
        const int r = gate * H + unit;
        const float* wr = Whh1 + r * H;
        #define LDW(V, J) V = make_float4(wr[(J)*4+0], wr[(J)*4+1], wr[(J)*4+2], wr[(J)*4+3])
        LDW(w0,0); LDW(w1,1); LDW(w2_,2); LDW(w3,3); LDW(w4,4); LDW(w5,5);
        LDW(w6,6); LDW(w7,7); LDW(w8,8); LDW(w9,9); LDW(w10,10); LDW(w11,11);
        #undef LDW
        w12 = make_float4(wr[48], wr[49], wr[50], 0.0f);
        bsum = bih1[r] + bhh1[r];
        wi1  = Wih1[r];
    }
    // Pin: make weight loads non-rematerializable; forces VGPR residency.
    PIN4(w0); PIN4(w1); PIN4(w2_); PIN4(w3); PIN4(w4); PIN4(w5); PIN4(w6);
    PIN4(w7); PIN4(w8); PIN4(w9); PIN4(w10); PIN4(w11); PIN4(w12);
    asm volatile("" : "+v"(bsum), "+v"(wi1));

    // ---- layer-2 weights (per-lane column + uniform scalars), named float4 ----
    float4 w2c, wh2c, b2c;
    w2c = make_float4(
        (lane < H) ? Wih2[0 * H + lane] : 0.0f,
        (lane < H) ? Wih2[1 * H + lane] : 0.0f,
        (lane < H) ? Wih2[2 * H + lane] : 0.0f,
        (lane < H) ? Wih2[3 * H + lane] : 0.0f);
    wh2c = make_float4(Whh2[0], Whh2[1], Whh2[2], Whh2[3]);
    b2c  = make_float4(bih2[0] + bhh2[0], bih2[1] + bhh2[1],
                       bih2[2] + bhh2[2], bih2[3] + bhh2[3]);
    PIN4(w2c); PIN4(wh2c); PIN4(b2c);

    if (tid < 56) { hbuf[0][tid] = 0.0f; hbuf[1][tid] = 0.0f; }
    if (tid == 0) { c2h2[0] = 0.0f; c2h2[1] = 0.0f; }
    __syncthreads();

    float c1 = 0.0f;
    float* out_row = out + (size_t)n * TL;
    const int rot = (n + (n >> 8)) & 3;   // decorrelate layer-2 wave across co-resident blocks

    for (int t = 0; t < TL; ++t) {
        const float* hprev = hbuf[(t & 1) ^ 1];   // h1(t-1)

        // ---- layer 2 for step t-1, one rotating wave (overlaps layer-1 below) ----
        if (t > 0 && wid == ((t + rot) & 3)) {
            layer2_step(hprev, lane, w2c, wh2c, b2c, c2h2, out_row + (t - 1));
        }

        // ---- layer 1: gate pre-activations (52 reg-FMAs, LDS b128 broadcasts) ----
        const float x = xrow[t];
        float a0 = fmaf(x, wi1, bsum), a1 = 0.0f, a2 = 0.0f, a3 = 0.0f;
        const float4* h4 = reinterpret_cast<const float4*>(hprev);
        #define DOT4(W, J) { const float4 hv = h4[J]; \
            a0 = fmaf((W).x, hv.x, a0); a1 = fmaf((W).y, hv.y, a1); \
            a2 = fmaf((W).z, hv.z, a2); a3 = fmaf((W).w, hv.w, a3); }
        DOT4(w0,0)  DOT4(w1,1)  DOT4(w2_,2)  DOT4(w3,3)  DOT4(w4,4)
        DOT4(w5,5)  DOT4(w6,6)  DOT4(w7,7)   DOT4(w8,8)  DOT4(w9,9)
        DOT4(w10,10) DOT4(w11,11) DOT4(w12,12)
        #undef DOT4
        const float a = (a0 + a1) + (a2 + a3);

        // activation: tanh for gate 2, sigmoid otherwise (branchless)
        const bool istanh = (gate == 2);
        const float s  = istanh ? (a + a) : a;
        const float sg = sigf(s);
        const float v  = istanh ? fmaf(2.0f, sg, -1.0f) : sg;

        // gather the quad's 4 gates via DPP (no LDS, no barrier)
        const float vi = quadb<0x00>(v);
        const float vf = quadb<0x55>(v);
        const float vg = quadb<0xAA>(v);
        const float vo = quadb<0xFF>(v);

        c1 = fmaf(vf, c1, vi * vg);
        const float h1 = vo * tanhfast(c1);
        if (uval && gate == 0) hbuf[t & 1][unit] = h1;

        __syncthreads();   // the single per-step barrier
    }

    // ---- drain: layer 2 for t = TL-1 ----
    if (wid == ((TL + rot) & 3)) {
        layer2_step(hbuf[(TL & 1) ^ 1], lane, w2c, wh2c, b2c, c2h2, out_row + (TL - 1));
    }
}

extern "C" void kernel_launch(void* const* d_in, const int* in_sizes, int n_in,
                              void* d_out, int out_size, void* d_ws, size_t ws_size,
                              hipStream_t stream) {
    const float* stim = (const float*)d_in[0];
    const float* Wih1 = (const float*)d_in[1];
    const float* Whh1 = (const float*)d_in[2];
    const float* bih1 = (const float*)d_in[3];
    const float* bhh1 = (const float*)d_in[4];
    const float* Wih2 = (const float*)d_in[5];
    const float* Whh2 = (const float*)d_in[6];
    const float* bih2 = (const float*)d_in[7];
    const float* bhh2 = (const float*)d_in[8];
    float* out = (float*)d_out;

    const int N = in_sizes[0] / TL;   // 1024
    lstm2_fused<<<dim3(N), dim3(256), 0, stream>>>(
        stim, Wih1, Whh1, bih1, bhh1, Wih2, Whh2, bih2, bhh2, out);
}

// Round 4
// 1745.321 us; speedup vs baseline: 1.2225x; 1.2225x over previous
//
#include <hip/hip_runtime.h>

// LSTM 2-layer scan: N=1024 rows, T=2048 sequential steps.
// Block (256 thr, 4 waves) per row; lane quad = 4 gates of one hidden unit.
// R1-R3: compiler refuses to keep the 52 loop-invariant weights VGPR-resident
// (VGPR_Count 48/52, dur identical across 3 structurally different sources;
// 237 VALU instr/wave/step vs ~90 expected). Hints exhausted -> force codegen:
// inline-asm v_pk_fma_f32 with weight pairs as named v2f asm operands
// (26 packed FMAs, weights MUST be arch VGPRs at every use).
// Layer 2: DPP/swizzle reduce (no bpermute addr VALU). 1 barrier/step.

constexpr int H  = 51;
constexpr int TL = 2048;

typedef float v2f __attribute__((ext_vector_type(2)));

__device__ __forceinline__ float rcpf(float x)   { return __builtin_amdgcn_rcpf(x); }
__device__ __forceinline__ float exp2f_(float x) { return __builtin_amdgcn_exp2f(x); }

constexpr float LOG2E  = 1.442695041f;
constexpr float LOG2E2 = 2.885390082f;

template <int CTRL>
__device__ __forceinline__ float dppmov(float v) {
    return __int_as_float(__builtin_amdgcn_update_dpp(
        0, __float_as_int(v), CTRL, 0xF, 0xF, true));
}

// full-wave sum, all 64 lanes end with the total
__device__ __forceinline__ float wave_sum(float p) {
    p += dppmov<0xB1>(p);     // quad_perm xor1
    p += dppmov<0x4E>(p);     // quad_perm xor2
    p += dppmov<0x124>(p);    // row_ror:4  (quad-uniform -> combines quads)
    p += dppmov<0x128>(p);    // row_ror:8  -> 16-lane row sum on all lanes
    p += __int_as_float(__builtin_amdgcn_ds_swizzle(__float_as_int(p), 0x401f)); // xor16
    p += __shfl_xor(p, 32, 64);                                                  // xor32
    return p;
}

template <int PAT>
__device__ __forceinline__ float quadb(float v) {
    // DPP quad_perm broadcast of quad-lane k (PAT = k*0x55)
    return __int_as_float(__builtin_amdgcn_update_dpp(
        0, __float_as_int(v), PAT, 0xF, 0xF, true));
}

__device__ __forceinline__ void pk_fma(v2f& acc, const v2f a, const v2f b) {
    // acc = a*b + acc, 2 x fp32 per instruction; forces a,b into arch VGPRs
    asm("v_pk_fma_f32 %0, %1, %2, %0" : "+v"(acc) : "v"(a), "v"(b));
}

__device__ __forceinline__ void layer2_step(
    const float* __restrict__ hprev, int lane,
    const float4& w2, const float4& wh2, const float4& b2,
    float* __restrict__ c2h2, float* __restrict__ out_ptr)
{
    const float hp = (lane < H) ? hprev[lane] : 0.0f;
    const float p0 = wave_sum(w2.x * hp);
    const float p1 = wave_sum(w2.y * hp);
    const float p2 = wave_sum(w2.z * hp);
    const float p3 = wave_sum(w2.w * hp);
    const float c2 = c2h2[0], h2 = c2h2[1];
    const float a0 = fmaf(wh2.x, h2, p0) + b2.x;
    const float a1 = fmaf(wh2.y, h2, p1) + b2.y;
    const float a2 = fmaf(wh2.z, h2, p2) + b2.z;
    const float a3 = fmaf(wh2.w, h2, p3) + b2.w;
    const float si = rcpf(1.0f + exp2f_(a0 * -LOG2E));
    const float sf = rcpf(1.0f + exp2f_(a1 * -LOG2E));
    const float tg = 1.0f - 2.0f * rcpf(1.0f + exp2f_(a2 * LOG2E2));
    const float so = rcpf(1.0f + exp2f_(a3 * -LOG2E));
    const float c2n = fmaf(sf, c2, si * tg);
    const float h2n = so * (1.0f - 2.0f * rcpf(1.0f + exp2f_(c2n * LOG2E2)));
    if (lane == 0) { c2h2[0] = c2n; c2h2[1] = h2n; *out_ptr = h2n; }
}

__global__ void
__attribute__((amdgpu_flat_work_group_size(256, 256)))
__attribute__((amdgpu_waves_per_eu(4, 4)))
lstm2_fused(const float* __restrict__ stim,
            const float* __restrict__ Wih1,
            const float* __restrict__ Whh1,
            const float* __restrict__ bih1,
            const float* __restrict__ bhh1,
            const float* __restrict__ Wih2,
            const float* __restrict__ Whh2,
            const float* __restrict__ bih2,
            const float* __restrict__ bhh2,
            float* __restrict__ out)
{
    const int n    = blockIdx.x;
    const int tid  = threadIdx.x;
    const int wid  = tid >> 6;
    const int lane = tid & 63;
    const int gate = lane & 3;                 // 0=i 1=f 2=g 3=o
    const int unit = wid * 16 + (lane >> 2);   // hidden unit, valid < 51
    const bool uval = (unit < H);

    __shared__ __align__(16) float xrow[TL];
    __shared__ __align__(16) float hbuf[2][56];
    __shared__ float c2h2[2];

    // ---- stage stimulus row to LDS, coalesced float4 ----
    {
        const float4* s4 = reinterpret_cast<const float4*>(stim + (size_t)n * TL);
        float4* d4 = reinterpret_cast<float4*>(xrow);
        d4[tid]       = s4[tid];
        d4[tid + 256] = s4[tid + 256];
    }

    // ---- layer-1 weights: 26 named v2f pairs (asm operands of pk_fma) ----
    v2f wa0, wb0, wa1, wb1, wa2, wb2, wa3, wb3, wa4, wb4, wa5, wb5,
        wa6, wb6, wa7, wb7, wa8, wb8, wa9, wb9, wa10, wb10, wa11, wb11,
        wa12, wb12;
    float bsum = 0.0f, wi1 = 0.0f;
    {
        const v2f z = {0.0f, 0.0f};
        wa0=z; wb0=z; wa1=z; wb1=z; wa2=z; wb2=z; wa3=z; wb3=z; wa4=z; wb4=z;
        wa5=z; wb5=z; wa6=z; wb6=z; wa7=z; wb7=z; wa8=z; wb8=z; wa9=z; wb9=z;
        wa10=z; wb10=z; wa11=z; wb11=z; wa12=z; wb12=z;
    }
    if (uval) {
        const int r = gate * H + unit;
        const float* wr = Whh1 + r * H;
        #define LDJ(J) wa##J = (v2f){wr[4*(J)+0], wr[4*(J)+1]}; \
                       wb##J = (v2f){wr[4*(J)+2], wr[4*(J)+3]};
        LDJ(0) LDJ(1) LDJ(2) LDJ(3) LDJ(4) LDJ(5)
        LDJ(6) LDJ(7) LDJ(8) LDJ(9) LDJ(10) LDJ(11)
        #undef LDJ
        wa12 = (v2f){wr[48], wr[49]};
        wb12 = (v2f){wr[50], 0.0f};
        bsum = bih1[r] + bhh1[r];
        wi1  = Wih1[r];
    }

    // ---- layer-2 weights ----
    float4 w2c, wh2c, b2c;
    w2c = make_float4(
        (lane < H) ? Wih2[0 * H + lane] : 0.0f,
        (lane < H) ? Wih2[1 * H + lane] : 0.0f,
        (lane < H) ? Wih2[2 * H + lane] : 0.0f,
        (lane < H) ? Wih2[3 * H + lane] : 0.0f);
    wh2c = make_float4(Whh2[0], Whh2[1], Whh2[2], Whh2[3]);
    b2c  = make_float4(bih2[0] + bhh2[0], bih2[1] + bhh2[1],
                       bih2[2] + bhh2[2], bih2[3] + bhh2[3]);

    if (tid < 56) { hbuf[0][tid] = 0.0f; hbuf[1][tid] = 0.0f; }
    if (tid == 0) { c2h2[0] = 0.0f; c2h2[1] = 0.0f; }
    __syncthreads();

    float c1 = 0.0f;
    float* out_row = out + (size_t)n * TL;
    const int rot = (n + (n >> 8)) & 3;

    for (int t = 0; t < TL; ++t) {
        const float* hprev = hbuf[(t & 1) ^ 1];   // h1(t-1)

        // ---- layer 2 for step t-1 on one rotating wave ----
        if (t > 0 && wid == ((t + rot) & 3)) {
            layer2_step(hprev, lane, w2c, wh2c, b2c, c2h2, out_row + (t - 1));
        }

        // ---- layer 1: 26 packed FMAs over LDS-broadcast h ----
        const float x = xrow[t];
        v2f acc0 = {fmaf(x, wi1, bsum), 0.0f};
        v2f acc1 = {0.0f, 0.0f};
        const float4* h4 = reinterpret_cast<const float4*>(hprev);
        #define DOT(J) { const float4 hv = h4[J]; \
            pk_fma(acc0, wa##J, (v2f){hv.x, hv.y}); \
            pk_fma(acc1, wb##J, (v2f){hv.z, hv.w}); }
        DOT(0) DOT(1) DOT(2) DOT(3) DOT(4) DOT(5)
        DOT(6) DOT(7) DOT(8) DOT(9) DOT(10) DOT(11) DOT(12)
        #undef DOT
        const float a = (acc0.x + acc1.x) + (acc0.y + acc1.y);

        // activation: sigmoid / tanh select via single exp2
        const bool  istanh = (gate == 2);
        const float k  = istanh ? LOG2E2 : -LOG2E;
        const float rr = rcpf(1.0f + exp2f_(a * k));
        const float v  = istanh ? fmaf(-2.0f, rr, 1.0f) : rr;

        // gather the quad's 4 gates via DPP
        const float vi = quadb<0x00>(v);
        const float vf = quadb<0x55>(v);
        const float vg = quadb<0xAA>(v);
        const float vo = quadb<0xFF>(v);

        c1 = fmaf(vf, c1, vi * vg);
        const float h1 = vo * (1.0f - 2.0f * rcpf(1.0f + exp2f_(c1 * LOG2E2)));
        if (uval && gate == 0) hbuf[t & 1][unit] = h1;

        __syncthreads();
    }

    // ---- drain: layer 2 for t = TL-1 ----
    if (wid == ((TL + rot) & 3)) {
        layer2_step(hbuf[(TL & 1) ^ 1], lane, w2c, wh2c, b2c, c2h2, out_row + (TL - 1));
    }
}

extern "C" void kernel_launch(void* const* d_in, const int* in_sizes, int n_in,
                              void* d_out, int out_size, void* d_ws, size_t ws_size,
                              hipStream_t stream) {
    const float* stim = (const float*)d_in[0];
    const float* Wih1 = (const float*)d_in[1];
    const float* Whh1 = (const float*)d_in[2];
    const float* bih1 = (const float*)d_in[3];
    const float* bhh1 = (const float*)d_in[4];
    const float* Wih2 = (const float*)d_in[5];
    const float* Whh2 = (const float*)d_in[6];
    const float* bih2 = (const float*)d_in[7];
    const float* bhh2 = (const float*)d_in[8];
    float* out = (float*)d_out;

    const int N = in_sizes[0] / TL;   // 1024
    lstm2_fused<<<dim3(N), dim3(256), 0, stream>>>(
        stim, Wih1, Whh1, bih1, bhh1, Wih2, Whh2, bih2, bhh2, out);
}